// Round 6
// baseline (228.528 us; speedup 1.0000x reference)
//
#include <hip/hip_runtime.h>
#include <hip/hip_fp16.h>

#define N_SEQ 8192
#define E_DIM 768
#define D_OUT 64
#define SCALE_LOG2 0.18033688011112042f   // 1/(8*ln2): fold softmax scale + log2e into Q

typedef __attribute__((ext_vector_type(8)))  short s16x8;
typedef __attribute__((ext_vector_type(4)))  float f32x4;
typedef __attribute__((ext_vector_type(16))) float f32x16;

static __device__ __forceinline__ unsigned short f2bf(float f) {
    union { float f; unsigned int u; } v; v.f = f;
    unsigned int r = v.u + 0x7FFFu + ((v.u >> 16) & 1u);   // RNE
    return (unsigned short)(r >> 16);
}
static __device__ __forceinline__ float bf2f(unsigned short h) {
    union { float f; unsigned int u; } v; v.u = ((unsigned int)h) << 16; return v.f;
}
// pack two f32 -> bf16x2 by truncation (bias cancels: same P feeds O and l)
static __device__ __forceinline__ unsigned int packbf(float a, float b) {
    union { float f; unsigned int u; } x, y; x.f = a; y.f = b;
    return (y.u & 0xFFFF0000u) | (x.u >> 16);
}
static __device__ __forceinline__ s16x8 gfrag(const unsigned short* p) {
    union { uint4 u; s16x8 s; } r; r.u = *(const uint4*)p; return r.s;
}

// ---------------- Kernel 1: X -> bf16 hi/lo AND W -> Wt hi/lo (merged) -------
#define NXB 6144    // (8192*768/4)/256 float4-blocks for the X part
__global__ __launch_bounds__(256) void prep(const float* __restrict__ X,
                                            const float* __restrict__ WQ,
                                            const float* __restrict__ WK,
                                            const float* __restrict__ WV,
                                            unsigned short* __restrict__ Xhi,
                                            unsigned short* __restrict__ Xlo,
                                            unsigned short* __restrict__ Wthi,
                                            unsigned short* __restrict__ Wtlo) {
    int b = blockIdx.x;
    if (b < NXB) {                          // X: coalesced float4 hi/lo split
        int idx = b * 256 + threadIdx.x;
        float4 v = ((const float4*)X)[idx];
        ushort4 hi, lo;
        hi.x = f2bf(v.x); lo.x = f2bf(v.x - bf2f(hi.x));
        hi.y = f2bf(v.y); lo.y = f2bf(v.y - bf2f(hi.y));
        hi.z = f2bf(v.z); lo.z = f2bf(v.z - bf2f(hi.z));
        hi.w = f2bf(v.w); lo.w = f2bf(v.w - bf2f(hi.w));
        ((ushort4*)Xhi)[idx] = hi;
        ((ushort4*)Xlo)[idx] = lo;
    } else {                                // W: transpose + hi/lo split
        int idx = (b - NXB) * 256 + threadIdx.x;   // 192*768 exact
        int n = idx / E_DIM;
        int k = idx - n * E_DIM;
        float v;
        if (n < 64)       v = WQ[k * 64 + n];
        else if (n < 128) v = WK[k * 64 + (n - 64)];
        else              v = WV[k * 64 + (n - 128)];
        unsigned short hb = f2bf(v);
        Wthi[idx] = hb;
        Wtlo[idx] = f2bf(v - bf2f(hb));
    }
}

// ---------------- Kernel 2: QKV projection (fused Q/K/V per wave) ------------
// Wave computes Q,K,V for one 16-row x 16-col block: X-frags loaded once,
// 7 MFMAs per 32-k step. 512 m-tiles x 4 col-blocks = 2048 wave-tasks.
__global__ __launch_bounds__(256, 4) void proj_qkv(const unsigned short* __restrict__ Xhi,
                                                   const unsigned short* __restrict__ Xlo,
                                                   const unsigned short* __restrict__ Wthi,
                                                   const unsigned short* __restrict__ Wtlo,
                                                   unsigned short* __restrict__ Qhi,
                                                   unsigned short* __restrict__ Qlo,
                                                   unsigned short* __restrict__ Khi,
                                                   unsigned short* __restrict__ Klo,
                                                   unsigned short* __restrict__ Vt) {
    int tid  = threadIdx.x;
    int wv   = tid >> 6;
    int lane = tid & 63;
    int id   = blockIdx.x * 4 + wv;          // 0..2047
    int mt   = id >> 2;
    int c    = id & 3;                       // 16-col block within D=64
    int m0 = mt * 16, n0 = c * 16;
    int lr = lane & 15, lk = lane >> 4;      // row-in-tile, k-quad

    f32x4 aQ, aK, aV;
    #pragma unroll
    for (int i = 0; i < 4; ++i) { aQ[i] = 0.f; aK[i] = 0.f; aV[i] = 0.f; }

    const unsigned short* xh  = Xhi  + (size_t)(m0 + lr) * E_DIM + lk * 8;
    const unsigned short* xl  = Xlo  + (size_t)(m0 + lr) * E_DIM + lk * 8;
    const unsigned short* wqh = Wthi + (size_t)(n0 + lr) * E_DIM + lk * 8;
    const unsigned short* wql = Wtlo + (size_t)(n0 + lr) * E_DIM + lk * 8;
    const unsigned short* wkh = Wthi + (size_t)(64 + n0 + lr) * E_DIM + lk * 8;
    const unsigned short* wkl = Wtlo + (size_t)(64 + n0 + lr) * E_DIM + lk * 8;
    const unsigned short* wvh = Wthi + (size_t)(128 + n0 + lr) * E_DIM + lk * 8;

    #pragma unroll 2
    for (int ks = 0; ks < E_DIM / 32; ++ks) {
        int kb = ks * 32;
        s16x8 ah = gfrag(xh + kb);
        s16x8 al = gfrag(xl + kb);
        s16x8 bqh = gfrag(wqh + kb);
        s16x8 bql = gfrag(wql + kb);
        s16x8 bkh = gfrag(wkh + kb);
        s16x8 bkl = gfrag(wkl + kb);
        s16x8 bvh = gfrag(wvh + kb);
        aQ = __builtin_amdgcn_mfma_f32_16x16x32_bf16(ah, bqh, aQ, 0, 0, 0);
        aK = __builtin_amdgcn_mfma_f32_16x16x32_bf16(ah, bkh, aK, 0, 0, 0);
        aV = __builtin_amdgcn_mfma_f32_16x16x32_bf16(ah, bvh, aV, 0, 0, 0);
        aQ = __builtin_amdgcn_mfma_f32_16x16x32_bf16(ah, bql, aQ, 0, 0, 0);
        aK = __builtin_amdgcn_mfma_f32_16x16x32_bf16(ah, bkl, aK, 0, 0, 0);
        aQ = __builtin_amdgcn_mfma_f32_16x16x32_bf16(al, bqh, aQ, 0, 0, 0);
        aK = __builtin_amdgcn_mfma_f32_16x16x32_bf16(al, bkh, aK, 0, 0, 0);
    }

    // C/D layout (16x16): col = lane&15, row = (lane>>4)*4 + r  [m89/m91]
    #pragma unroll
    for (int r = 0; r < 4; ++r) {
        int grow = m0 + lk * 4 + r, gcol = n0 + lr;
        float q = aQ[r] * SCALE_LOG2;
        unsigned short hb = f2bf(q);
        Qhi[(size_t)grow * 64 + gcol] = hb;
        Qlo[(size_t)grow * 64 + gcol] = f2bf(q - bf2f(hb));
        float v = aK[r];
        hb = f2bf(v);
        Khi[(size_t)grow * 64 + gcol] = hb;
        Klo[(size_t)grow * 64 + gcol] = f2bf(v - bf2f(hb));
    }
    ushort4 pk;                          // V: 4 consecutive rows -> one 8B store
    pk.x = f2bf(aV[0]); pk.y = f2bf(aV[1]);
    pk.z = f2bf(aV[2]); pk.w = f2bf(aV[3]);
    *(ushort4*)(Vt + (size_t)(n0 + lr) * N_SEQ + m0 + lk * 4) = pk;
}

// ---------------- Kernel 3: flash attention — LDS-free, barrier-free ---------
// grid (nsplit, 64); block 256 = 4 waves, each wave owns 32 Q-rows and
// free-runs over its KV chunk. S^T = K*Q^T: K-frags (A: m=key, k=d) and
// V-frags (B: n=d, k=key) load DIRECTLY from global (L2-resident, 3 MB
// total; 4 waves/block share addresses -> L1 hits). No __syncthreads at all.
__global__ __launch_bounds__(256, 3) void attn(const unsigned short* __restrict__ Qhi,
                                               const unsigned short* __restrict__ Qlo,
                                               const unsigned short* __restrict__ Khi,
                                               const unsigned short* __restrict__ Klo,
                                               const unsigned short* __restrict__ Vt,
                                               unsigned short* __restrict__ Opart,
                                               float* __restrict__ mpart,
                                               float* __restrict__ lpart,
                                               int chunk) {
    int tid = threadIdx.x, wv = tid >> 6, lane = tid & 63;
    int lrow = lane & 31, lh = lane >> 5;
    int c = blockIdx.x, qb = blockIdx.y;
    int q0 = qb * 128 + wv * 32;

    // Q fragments (whole D=64) resident in registers
    s16x8 qh[4], ql[4];
    #pragma unroll
    for (int ks = 0; ks < 4; ++ks) {
        int kb = ks * 16 + lh * 8;
        qh[ks] = gfrag(Qhi + (size_t)(q0 + lrow) * 64 + kb);
        ql[ks] = gfrag(Qlo + (size_t)(q0 + lrow) * 64 + kb);
    }

    f32x16 O0, O1;
    #pragma unroll
    for (int i = 0; i < 16; ++i) { O0[i] = 0.f; O1[i] = 0.f; }
    float mrow = -1e30f, lrun = 0.f;

    int steps = chunk >> 6;

    for (int it = 0; it < steps; ++it) {
        int j0 = c * chunk + it * 64;

        // ---- S^T = K @ Q^T (3-term split-bf16); K-frags straight from global
        f32x16 s0, s1;
        #pragma unroll
        for (int i = 0; i < 16; ++i) { s0[i] = 0.f; s1[i] = 0.f; }
        const unsigned short* kh0 = Khi + (size_t)(j0 + lrow) * 64 + lh * 8;
        const unsigned short* kl0 = Klo + (size_t)(j0 + lrow) * 64 + lh * 8;
        const unsigned short* kh1 = kh0 + 32 * 64;
        const unsigned short* kl1 = kl0 + 32 * 64;
        #pragma unroll
        for (int ks = 0; ks < 4; ++ks) {
            s16x8 a0h = gfrag(kh0 + ks * 16);
            s16x8 a0l = gfrag(kl0 + ks * 16);
            s16x8 a1h = gfrag(kh1 + ks * 16);
            s16x8 a1l = gfrag(kl1 + ks * 16);
            s0 = __builtin_amdgcn_mfma_f32_32x32x16_bf16(a0h, qh[ks], s0, 0, 0, 0);
            s0 = __builtin_amdgcn_mfma_f32_32x32x16_bf16(a0l, qh[ks], s0, 0, 0, 0);
            s0 = __builtin_amdgcn_mfma_f32_32x32x16_bf16(a0h, ql[ks], s0, 0, 0, 0);
            s1 = __builtin_amdgcn_mfma_f32_32x32x16_bf16(a1h, qh[ks], s1, 0, 0, 0);
            s1 = __builtin_amdgcn_mfma_f32_32x32x16_bf16(a1l, qh[ks], s1, 0, 0, 0);
            s1 = __builtin_amdgcn_mfma_f32_32x32x16_bf16(a1h, ql[ks], s1, 0, 0, 0);
        }

        // ---- in-lane row max (this lane's query = lrow)
        float rm = s0[0];
        #pragma unroll
        for (int i = 1; i < 16; ++i) rm = fmaxf(rm, s0[i]);
        #pragma unroll
        for (int i = 0; i < 16; ++i) rm = fmaxf(rm, s1[i]);
        rm = fmaxf(rm, __shfl_xor(rm, 32, 64));
        float mn  = fmaxf(mrow, rm);
        float alf = exp2f(mrow - mn);
        mrow = mn;

        // ---- p = exp2(s - m) in place; partial row-sum
        float psum = 0.f;
        #pragma unroll
        for (int i = 0; i < 16; ++i) { s0[i] = exp2f(s0[i] - mn); psum += s0[i]; }
        #pragma unroll
        for (int i = 0; i < 16; ++i) { s1[i] = exp2f(s1[i] - mn); psum += s1[i]; }
        lrun = lrun * alf + psum;

        // ---- pack P to bf16 pairs; lane^32 swap builds A-frags (query=m)
        unsigned int I[16], J[16];
        #pragma unroll
        for (int q4 = 0; q4 < 4; ++q4) {
            I[2 * q4]         = packbf(s0[4 * q4],     s0[4 * q4 + 1]);
            I[2 * q4 + 1]     = packbf(s0[4 * q4 + 2], s0[4 * q4 + 3]);
            I[8 + 2 * q4]     = packbf(s1[4 * q4],     s1[4 * q4 + 1]);
            I[8 + 2 * q4 + 1] = packbf(s1[4 * q4 + 2], s1[4 * q4 + 3]);
        }
        #pragma unroll
        for (int i = 0; i < 16; ++i) J[i] = (unsigned int)__shfl_xor((int)I[i], 32, 64);
        s16x8 a[4];
        #pragma unroll
        for (int ks = 0; ks < 4; ++ks) {
            int b = (ks >> 1) * 8 + (ks & 1) * 4;
            union { unsigned int u[4]; s16x8 s; } fa;
            fa.u[0] = lh ? J[b + 2] : I[b];
            fa.u[1] = lh ? J[b + 3] : I[b + 1];
            fa.u[2] = lh ? I[b + 2] : J[b];
            fa.u[3] = lh ? I[b + 3] : J[b + 1];
            a[ks] = fa.s;
        }

        // ---- rescale O only when some query's max moved (skip when alf==1)
        if (__any(alf != 1.0f)) {
            #pragma unroll
            for (int r = 0; r < 16; ++r) {
                int qr = (r & 3) + 8 * (r >> 2) + 4 * lh;
                float af = __shfl(alf, qr, 64);
                O0[r] *= af; O1[r] *= af;
            }
        }

        // ---- O += P @ V ; V-frags straight from global (B: n=d=lrow, k=key)
        const unsigned short* vb0 = Vt + (size_t)lrow * N_SEQ + j0 + lh * 8;
        const unsigned short* vb1 = vb0 + 32 * N_SEQ;
        #pragma unroll
        for (int ks = 0; ks < 4; ++ks) {
            s16x8 b0 = gfrag(vb0 + ks * 16);
            s16x8 b1 = gfrag(vb1 + ks * 16);
            O0 = __builtin_amdgcn_mfma_f32_32x32x16_bf16(a[ks], b0, O0, 0, 0, 0);
            O1 = __builtin_amdgcn_mfma_f32_32x32x16_bf16(a[ks], b1, O1, 0, 0, 0);
        }
    }

    // ---- store partials (O as bf16: halves split-K traffic)
    #pragma unroll
    for (int r = 0; r < 16; ++r) {
        int row = (r & 3) + 8 * (r >> 2) + 4 * lh;
        int grow = q0 + row;
        size_t ob = ((size_t)c * N_SEQ + grow) * 64;
        Opart[ob + lrow]      = f2bf(O0[r]);
        Opart[ob + 32 + lrow] = f2bf(O1[r]);
    }
    float lfull = lrun + __shfl_xor(lrun, 32, 64);
    if (lane < 32) {
        int grow = q0 + lrow;
        mpart[c * N_SEQ + grow] = mrow;
        lpart[c * N_SEQ + grow] = lfull;
    }
}

// ---------------- Kernel 4: combine split-K partials (bf16 partials) ---------
__global__ __launch_bounds__(256) void combine(const unsigned short* __restrict__ Opart,
                                               const float* __restrict__ mpart,
                                               const float* __restrict__ lpart,
                                               float* __restrict__ out,
                                               int nsplit) {
    int idx = blockIdx.x * 256 + threadIdx.x;    // N_SEQ*16
    int row = idx >> 4, d4 = idx & 15;
    float M = -1e30f;
    #pragma unroll 4
    for (int c = 0; c < nsplit; ++c) M = fmaxf(M, mpart[c * N_SEQ + row]);
    float4 num = make_float4(0.f, 0.f, 0.f, 0.f);
    float den = 0.f;
    #pragma unroll 4
    for (int c = 0; c < nsplit; ++c) {
        float w = exp2f(mpart[c * N_SEQ + row] - M);
        den += w * lpart[c * N_SEQ + row];
        ushort4 o = *(const ushort4*)(Opart + ((size_t)c * N_SEQ + row) * 64 + d4 * 4);
        num.x += w * bf2f(o.x); num.y += w * bf2f(o.y);
        num.z += w * bf2f(o.z); num.w += w * bf2f(o.w);
    }
    float inv = 1.0f / den;
    num.x *= inv; num.y *= inv; num.z *= inv; num.w *= inv;
    ((float4*)out)[idx] = num;
}

extern "C" void kernel_launch(void* const* d_in, const int* in_sizes, int n_in,
                              void* d_out, int out_size, void* d_ws, size_t ws_size,
                              hipStream_t stream) {
    const float* X  = (const float*)d_in[0];
    const float* WQ = (const float*)d_in[1];
    const float* WK = (const float*)d_in[2];
    const float* WV = (const float*)d_in[3];
    float* out = (float*)d_out;

    // workspace carve
    const size_t szQK = (size_t)N_SEQ * 64 * 2;      // 1 MB each (bf16)
    const size_t szW  = (size_t)192 * E_DIM * 2;     // 288 KB each
    const size_t szX  = (size_t)N_SEQ * E_DIM * 2;   // 12.6 MB each (bf16)
    char* p = (char*)d_ws;
    unsigned short* Qhi = (unsigned short*)p; p += szQK;
    unsigned short* Qlo = (unsigned short*)p; p += szQK;
    unsigned short* Khi = (unsigned short*)p; p += szQK;
    unsigned short* Klo = (unsigned short*)p; p += szQK;
    unsigned short* Vt  = (unsigned short*)p; p += szQK;
    unsigned short* Wthi = (unsigned short*)p; p += szW;
    unsigned short* Wtlo = (unsigned short*)p; p += szW;
    unsigned short* Xhi = (unsigned short*)p; p += szX;
    unsigned short* Xlo = (unsigned short*)p; p += szX;
    size_t base = (size_t)(p - (char*)d_ws);
    size_t per  = (size_t)N_SEQ * 64 * 2 + 2 * (size_t)N_SEQ * 4;  // bf16 Opart + m + l
    int nsplit = 16;
    while (nsplit > 1 && base + (size_t)nsplit * per > ws_size) nsplit >>= 1;
    float* mpart = (float*)p; p += (size_t)nsplit * N_SEQ * 4;
    float* lpart = (float*)p; p += (size_t)nsplit * N_SEQ * 4;
    unsigned short* Opart = (unsigned short*)p;

    int chunk = N_SEQ / nsplit;

    prep<<<NXB + (192 * E_DIM) / 256, 256, 0, stream>>>(X, WQ, WK, WV,
                                                        Xhi, Xlo, Wthi, Wtlo);
    proj_qkv<<<512, 256, 0, stream>>>(Xhi, Xlo, Wthi, Wtlo, Qhi, Qlo, Khi, Klo, Vt);
    attn<<<dim3(nsplit, N_SEQ / 128), 256, 0, stream>>>(Qhi, Qlo, Khi, Klo, Vt,
                                                        Opart, mpart, lpart, chunk);
    combine<<<(N_SEQ * 16 + 255) / 256, 256, 0, stream>>>(Opart, mpart, lpart, out, nsplit);
}

// Round 7
// 195.268 us; speedup vs baseline: 1.1703x; 1.1703x over previous
//
#include <hip/hip_runtime.h>
#include <hip/hip_fp16.h>

#define N_SEQ 8192
#define E_DIM 768
#define D_OUT 64
#define PADK 68                       // 64 + 4 pad -> 136B rows: 2-way (free) bank aliasing
#define SCALE_LOG2 0.18033688011112042f   // 1/(8*ln2): fold softmax scale + log2e into Q

typedef __attribute__((ext_vector_type(8)))  short s16x8;
typedef __attribute__((ext_vector_type(4)))  float f32x4;
typedef __attribute__((ext_vector_type(16))) float f32x16;

static __device__ __forceinline__ unsigned short f2bf(float f) {
    union { float f; unsigned int u; } v; v.f = f;
    unsigned int r = v.u + 0x7FFFu + ((v.u >> 16) & 1u);   // RNE
    return (unsigned short)(r >> 16);
}
static __device__ __forceinline__ float bf2f(unsigned short h) {
    union { float f; unsigned int u; } v; v.u = ((unsigned int)h) << 16; return v.f;
}
// pack two f32 -> bf16x2 by truncation (bias cancels / compensated by lo term)
static __device__ __forceinline__ unsigned int packbf(float a, float b) {
    union { float f; unsigned int u; } x, y; x.f = a; y.f = b;
    return (y.u & 0xFFFF0000u) | (x.u >> 16);
}
static __device__ __forceinline__ s16x8 gfrag(const unsigned short* p) {
    union { uint4 u; s16x8 s; } r; r.u = *(const uint4*)p; return r.s;
}
static __device__ __forceinline__ s16x8 ldsfrag(const unsigned short* p) {
    union { uint2 u[2]; s16x8 s; } r;
    r.u[0] = *(const uint2*)(p);
    r.u[1] = *(const uint2*)(p + 4);
    return r.s;
}
static __device__ __forceinline__ void st32(unsigned short* d, uint4 a, uint4 b) {
    uint2* p = (uint2*)d;
    p[0] = make_uint2(a.x, a.y); p[1] = make_uint2(a.z, a.w);
    p[2] = make_uint2(b.x, b.y); p[3] = make_uint2(b.z, b.w);
}

// ---------------- Kernel 1: W -> Wt (transposed, bf16 hi/lo) -----------------
__global__ __launch_bounds__(256) void prep_w(const float* __restrict__ WQ,
                                              const float* __restrict__ WK,
                                              const float* __restrict__ WV,
                                              unsigned short* __restrict__ Wthi,
                                              unsigned short* __restrict__ Wtlo) {
    int idx = blockIdx.x * 256 + threadIdx.x;          // 192*768 exact
    int n = idx / E_DIM;
    int k = idx - n * E_DIM;
    float v;
    if (n < 64)       v = WQ[k * 64 + n];
    else if (n < 128) v = WK[k * 64 + (n - 64)];
    else              v = WV[k * 64 + (n - 128)];
    unsigned short hb = f2bf(v);
    Wthi[idx] = hb;
    Wtlo[idx] = f2bf(v - bf2f(hb));
}

// ---------------- Kernel 2: QKV projection (fp32 X, in-register split) -------
// Block = one 16-row m-tile; wave wv = 16-col block c=wv of D. The 4 waves
// share the same X rows (L1 hits). X hi/lo split in-register: hi = trunc,
// lo = RNE(v - hi) -> hi+lo accurate to 2^-17, ~32 VALU/step.
__global__ __launch_bounds__(256, 2) void proj_qkv(const float* __restrict__ X,
                                                   const unsigned short* __restrict__ Wthi,
                                                   const unsigned short* __restrict__ Wtlo,
                                                   unsigned short* __restrict__ Qhi,
                                                   unsigned short* __restrict__ Qlo,
                                                   unsigned short* __restrict__ Khi,
                                                   unsigned short* __restrict__ Klo,
                                                   unsigned short* __restrict__ Vt) {
    int tid  = threadIdx.x;
    int wv   = tid >> 6;
    int lane = tid & 63;
    int mt   = blockIdx.x;                   // 0..511
    int c    = wv;                           // 16-col block within D=64
    int m0 = mt * 16, n0 = c * 16;
    int lr = lane & 15, lk = lane >> 4;      // row-in-tile, k-quad

    f32x4 aQ, aK, aV;
    #pragma unroll
    for (int i = 0; i < 4; ++i) { aQ[i] = 0.f; aK[i] = 0.f; aV[i] = 0.f; }

    const float* xb = X + (size_t)(m0 + lr) * E_DIM + lk * 8;
    const unsigned short* wqh = Wthi + (size_t)(n0 + lr) * E_DIM + lk * 8;
    const unsigned short* wql = Wtlo + (size_t)(n0 + lr) * E_DIM + lk * 8;
    const unsigned short* wkh = Wthi + (size_t)(64 + n0 + lr) * E_DIM + lk * 8;
    const unsigned short* wkl = Wtlo + (size_t)(64 + n0 + lr) * E_DIM + lk * 8;
    const unsigned short* wvh = Wthi + (size_t)(128 + n0 + lr) * E_DIM + lk * 8;

    #pragma unroll 2
    for (int ks = 0; ks < E_DIM / 32; ++ks) {
        int kb = ks * 32;
        union { float4 f[2]; float s[8]; unsigned int u[8]; } xv;
        xv.f[0] = *(const float4*)(xb + kb);
        xv.f[1] = *(const float4*)(xb + kb + 4);
        // split: hi = trunc(v); lo = trunc(v - hi)  (compensated)
        union { unsigned int u[4]; s16x8 s; } ah, al;
        #pragma unroll
        for (int j = 0; j < 4; ++j) {
            union { unsigned int u; float f; } h0, h1;
            h0.u = xv.u[2 * j]     & 0xFFFF0000u;
            h1.u = xv.u[2 * j + 1] & 0xFFFF0000u;
            ah.u[j] = (xv.u[2 * j] >> 16) | (xv.u[2 * j + 1] & 0xFFFF0000u);
            al.u[j] = packbf(xv.s[2 * j] - h0.f, xv.s[2 * j + 1] - h1.f);
        }
        s16x8 bqh = gfrag(wqh + kb);
        s16x8 bql = gfrag(wql + kb);
        s16x8 bkh = gfrag(wkh + kb);
        s16x8 bkl = gfrag(wkl + kb);
        s16x8 bvh = gfrag(wvh + kb);
        aQ = __builtin_amdgcn_mfma_f32_16x16x32_bf16(ah.s, bqh, aQ, 0, 0, 0);
        aK = __builtin_amdgcn_mfma_f32_16x16x32_bf16(ah.s, bkh, aK, 0, 0, 0);
        aV = __builtin_amdgcn_mfma_f32_16x16x32_bf16(ah.s, bvh, aV, 0, 0, 0);
        aQ = __builtin_amdgcn_mfma_f32_16x16x32_bf16(ah.s, bql, aQ, 0, 0, 0);
        aK = __builtin_amdgcn_mfma_f32_16x16x32_bf16(ah.s, bkl, aK, 0, 0, 0);
        aQ = __builtin_amdgcn_mfma_f32_16x16x32_bf16(al.s, bqh, aQ, 0, 0, 0);
        aK = __builtin_amdgcn_mfma_f32_16x16x32_bf16(al.s, bkh, aK, 0, 0, 0);
    }

    // C/D layout (16x16): col = lane&15, row = (lane>>4)*4 + r  [m89/m91]
    #pragma unroll
    for (int r = 0; r < 4; ++r) {
        int grow = m0 + lk * 4 + r, gcol = n0 + lr;
        float q = aQ[r] * SCALE_LOG2;
        unsigned short hb = f2bf(q);
        Qhi[(size_t)grow * 64 + gcol] = hb;
        Qlo[(size_t)grow * 64 + gcol] = f2bf(q - bf2f(hb));
        float v = aK[r];
        hb = f2bf(v);
        Khi[(size_t)grow * 64 + gcol] = hb;
        Klo[(size_t)grow * 64 + gcol] = f2bf(v - bf2f(hb));
    }
    ushort4 pk;                          // V: 4 consecutive rows -> one 8B store
    pk.x = f2bf(aV[0]); pk.y = f2bf(aV[1]);
    pk.z = f2bf(aV[2]); pk.w = f2bf(aV[3]);
    *(ushort4*)(Vt + (size_t)(n0 + lr) * N_SEQ + m0 + lk * 4) = pk;
}

// ---------------- Kernel 3: flash attention (S^T form + prefetch) ------------
// grid (nsplit, 64); block 256 = 4 waves, each wave owns 32 Q-rows.
// R5-proven structure: LDS staging (coalesced), register prefetch of next
// tile, S^T = K*Q^T (in-lane scalar m/l, lane^32 P-transpose, no LDS P).
__global__ __launch_bounds__(256, 3) void attn(const unsigned short* __restrict__ Qhi,
                                               const unsigned short* __restrict__ Qlo,
                                               const unsigned short* __restrict__ Khi,
                                               const unsigned short* __restrict__ Klo,
                                               const unsigned short* __restrict__ Vt,
                                               unsigned short* __restrict__ Opart,
                                               float* __restrict__ mpart,
                                               float* __restrict__ lpart,
                                               int chunk) {
    __shared__ unsigned short sK[128 * PADK];   // rows 0-63 Khi, 64-127 Klo
    __shared__ unsigned short sV [64 * PADK];   // [d][key]

    int tid = threadIdx.x, wv = tid >> 6, lane = tid & 63;
    int lrow = lane & 31, lh = lane >> 5;
    int c = blockIdx.x, qb = blockIdx.y;
    int q0 = qb * 128 + wv * 32;

    // Q fragments (whole D=64) resident in registers
    s16x8 qh[4], ql[4];
    #pragma unroll
    for (int ks = 0; ks < 4; ++ks) {
        int kb = ks * 16 + lh * 8;
        qh[ks] = gfrag(Qhi + (size_t)(q0 + lrow) * 64 + kb);
        ql[ks] = gfrag(Qlo + (size_t)(q0 + lrow) * 64 + kb);
    }

    f32x16 O0, O1;
    #pragma unroll
    for (int i = 0; i < 16; ++i) { O0[i] = 0.f; O1[i] = 0.f; }
    float mrow = -1e30f, lrun = 0.f;

    int steps = chunk >> 6;
    int srow = tid >> 2, sseg = tid & 3;    // staging: 64 rows x 4 segs x 16 elems

    // prefetch tile 0
    uint4 rA0, rA1, rB0, rB1, rC0, rC1;
    {
        int j1 = c * chunk;
        const uint4* ps = (const uint4*)(Khi + ((size_t)(j1 + srow) * 64 + sseg * 16));
        rA0 = ps[0]; rA1 = ps[1];
        ps = (const uint4*)(Klo + ((size_t)(j1 + srow) * 64 + sseg * 16));
        rB0 = ps[0]; rB1 = ps[1];
        ps = (const uint4*)(Vt + ((size_t)srow * N_SEQ + j1 + sseg * 16));
        rC0 = ps[0]; rC1 = ps[1];
    }

    for (int it = 0; it < steps; ++it) {
        __syncthreads();                     // all waves done reading prev tile
        st32(sK + srow * PADK + sseg * 16, rA0, rA1);
        st32(sK + (64 + srow) * PADK + sseg * 16, rB0, rB1);
        st32(sV + srow * PADK + sseg * 16, rC0, rC1);
        __syncthreads();

        if (it + 1 < steps) {                // prefetch next tile (waits at next st32)
            int j1 = c * chunk + (it + 1) * 64;
            const uint4* ps = (const uint4*)(Khi + ((size_t)(j1 + srow) * 64 + sseg * 16));
            rA0 = ps[0]; rA1 = ps[1];
            ps = (const uint4*)(Klo + ((size_t)(j1 + srow) * 64 + sseg * 16));
            rB0 = ps[0]; rB1 = ps[1];
            ps = (const uint4*)(Vt + ((size_t)srow * N_SEQ + j1 + sseg * 16));
            rC0 = ps[0]; rC1 = ps[1];
        }

        // S^T = K @ Q^T  (3-term split-bf16): s0 keys 0-31, s1 keys 32-63
        f32x16 s0, s1;
        #pragma unroll
        for (int i = 0; i < 16; ++i) { s0[i] = 0.f; s1[i] = 0.f; }
        #pragma unroll
        for (int ks = 0; ks < 4; ++ks) {
            int kb = ks * 16 + lh * 8;
            s16x8 b0h = ldsfrag(sK + (size_t)lrow * PADK + kb);
            s16x8 b0l = ldsfrag(sK + (size_t)(64 + lrow) * PADK + kb);
            s0 = __builtin_amdgcn_mfma_f32_32x32x16_bf16(b0h, qh[ks], s0, 0, 0, 0);
            s0 = __builtin_amdgcn_mfma_f32_32x32x16_bf16(b0l, qh[ks], s0, 0, 0, 0);
            s0 = __builtin_amdgcn_mfma_f32_32x32x16_bf16(b0h, ql[ks], s0, 0, 0, 0);
            s16x8 b1h = ldsfrag(sK + (size_t)(32 + lrow) * PADK + kb);
            s16x8 b1l = ldsfrag(sK + (size_t)(96 + lrow) * PADK + kb);
            s1 = __builtin_amdgcn_mfma_f32_32x32x16_bf16(b1h, qh[ks], s1, 0, 0, 0);
            s1 = __builtin_amdgcn_mfma_f32_32x32x16_bf16(b1l, qh[ks], s1, 0, 0, 0);
            s1 = __builtin_amdgcn_mfma_f32_32x32x16_bf16(b1h, ql[ks], s1, 0, 0, 0);
        }

        // in-lane row max (this lane's query = lrow; other 32 keys in lane^32)
        float rm = s0[0];
        #pragma unroll
        for (int i = 1; i < 16; ++i) rm = fmaxf(rm, s0[i]);
        #pragma unroll
        for (int i = 0; i < 16; ++i) rm = fmaxf(rm, s1[i]);
        rm = fmaxf(rm, __shfl_xor(rm, 32, 64));
        float mn  = fmaxf(mrow, rm);
        float alf = exp2f(mrow - mn);
        mrow = mn;

        // p = exp2(s - m) in place; partial row-sum
        float psum = 0.f;
        #pragma unroll
        for (int i = 0; i < 16; ++i) { s0[i] = exp2f(s0[i] - mn); psum += s0[i]; }
        #pragma unroll
        for (int i = 0; i < 16; ++i) { s1[i] = exp2f(s1[i] - mn); psum += s1[i]; }
        lrun = lrun * alf + psum;

        // pack P to bf16 pairs; lane^32 swap builds A-frags (query=m)
        unsigned int I[16], J[16];
        #pragma unroll
        for (int q4 = 0; q4 < 4; ++q4) {
            I[2 * q4]         = packbf(s0[4 * q4],     s0[4 * q4 + 1]);
            I[2 * q4 + 1]     = packbf(s0[4 * q4 + 2], s0[4 * q4 + 3]);
            I[8 + 2 * q4]     = packbf(s1[4 * q4],     s1[4 * q4 + 1]);
            I[8 + 2 * q4 + 1] = packbf(s1[4 * q4 + 2], s1[4 * q4 + 3]);
        }
        #pragma unroll
        for (int i = 0; i < 16; ++i) J[i] = (unsigned int)__shfl_xor((int)I[i], 32, 64);
        s16x8 a[4];
        #pragma unroll
        for (int ks = 0; ks < 4; ++ks) {
            int b = (ks >> 1) * 8 + (ks & 1) * 4;
            union { unsigned int u[4]; s16x8 s; } fa;
            fa.u[0] = lh ? J[b + 2] : I[b];
            fa.u[1] = lh ? J[b + 3] : I[b + 1];
            fa.u[2] = lh ? I[b + 2] : J[b];
            fa.u[3] = lh ? I[b + 3] : J[b + 1];
            a[ks] = fa.s;
        }

        // rescale O only when some query's max moved (skip when alf==1)
        if (__any(alf != 1.0f)) {
            #pragma unroll
            for (int r = 0; r < 16; ++r) {
                int qr = (r & 3) + 8 * (r >> 2) + 4 * lh;
                float af = __shfl(alf, qr, 64);
                O0[r] *= af; O1[r] *= af;
            }
        }

        // O += P @ V
        #pragma unroll
        for (int ks = 0; ks < 4; ++ks) {
            int kb = ks * 16 + lh * 8;
            s16x8 b0 = ldsfrag(sV + (size_t)lrow * PADK + kb);
            s16x8 b1 = ldsfrag(sV + (size_t)(32 + lrow) * PADK + kb);
            O0 = __builtin_amdgcn_mfma_f32_32x32x16_bf16(a[ks], b0, O0, 0, 0, 0);
            O1 = __builtin_amdgcn_mfma_f32_32x32x16_bf16(a[ks], b1, O1, 0, 0, 0);
        }
    }

    // store partials (O as bf16: halves split-K traffic)
    #pragma unroll
    for (int r = 0; r < 16; ++r) {
        int row = (r & 3) + 8 * (r >> 2) + 4 * lh;
        int grow = q0 + row;
        size_t ob = ((size_t)c * N_SEQ + grow) * 64;
        Opart[ob + lrow]      = f2bf(O0[r]);
        Opart[ob + 32 + lrow] = f2bf(O1[r]);
    }
    float lfull = lrun + __shfl_xor(lrun, 32, 64);
    if (lane < 32) {
        int grow = q0 + lrow;
        mpart[c * N_SEQ + grow] = mrow;
        lpart[c * N_SEQ + grow] = lfull;
    }
}

// ---------------- Kernel 4: combine split-K partials (bf16 partials) ---------
__global__ __launch_bounds__(256) void combine(const unsigned short* __restrict__ Opart,
                                               const float* __restrict__ mpart,
                                               const float* __restrict__ lpart,
                                               float* __restrict__ out,
                                               int nsplit) {
    int idx = blockIdx.x * 256 + threadIdx.x;    // N_SEQ*16
    int row = idx >> 4, d4 = idx & 15;
    float M = -1e30f;
    #pragma unroll 4
    for (int c = 0; c < nsplit; ++c) M = fmaxf(M, mpart[c * N_SEQ + row]);
    float4 num = make_float4(0.f, 0.f, 0.f, 0.f);
    float den = 0.f;
    #pragma unroll 4
    for (int c = 0; c < nsplit; ++c) {
        float w = exp2f(mpart[c * N_SEQ + row] - M);
        den += w * lpart[c * N_SEQ + row];
        ushort4 o = *(const ushort4*)(Opart + ((size_t)c * N_SEQ + row) * 64 + d4 * 4);
        num.x += w * bf2f(o.x); num.y += w * bf2f(o.y);
        num.z += w * bf2f(o.z); num.w += w * bf2f(o.w);
    }
    float inv = 1.0f / den;
    num.x *= inv; num.y *= inv; num.z *= inv; num.w *= inv;
    ((float4*)out)[idx] = num;
}

extern "C" void kernel_launch(void* const* d_in, const int* in_sizes, int n_in,
                              void* d_out, int out_size, void* d_ws, size_t ws_size,
                              hipStream_t stream) {
    const float* X  = (const float*)d_in[0];
    const float* WQ = (const float*)d_in[1];
    const float* WK = (const float*)d_in[2];
    const float* WV = (const float*)d_in[3];
    float* out = (float*)d_out;

    // workspace carve
    const size_t szQK = (size_t)N_SEQ * 64 * 2;      // 1 MB each (bf16)
    const size_t szW  = (size_t)192 * E_DIM * 2;     // 288 KB each
    char* p = (char*)d_ws;
    unsigned short* Qhi = (unsigned short*)p; p += szQK;
    unsigned short* Qlo = (unsigned short*)p; p += szQK;
    unsigned short* Khi = (unsigned short*)p; p += szQK;
    unsigned short* Klo = (unsigned short*)p; p += szQK;
    unsigned short* Vt  = (unsigned short*)p; p += szQK;
    unsigned short* Wthi = (unsigned short*)p; p += szW;
    unsigned short* Wtlo = (unsigned short*)p; p += szW;
    size_t base = (size_t)(p - (char*)d_ws);
    size_t per  = (size_t)N_SEQ * 64 * 2 + 2 * (size_t)N_SEQ * 4;  // bf16 Opart + m + l
    int nsplit = 32;
    while (nsplit > 1 && base + (size_t)nsplit * per > ws_size) nsplit >>= 1;
    float* mpart = (float*)p; p += (size_t)nsplit * N_SEQ * 4;
    float* lpart = (float*)p; p += (size_t)nsplit * N_SEQ * 4;
    unsigned short* Opart = (unsigned short*)p;

    int chunk = N_SEQ / nsplit;

    prep_w<<<(192 * E_DIM) / 256, 256, 0, stream>>>(WQ, WK, WV, Wthi, Wtlo);
    proj_qkv<<<512, 256, 0, stream>>>(X, Wthi, Wtlo, Qhi, Qlo, Khi, Klo, Vt);
    attn<<<dim3(nsplit, N_SEQ / 128), 256, 0, stream>>>(Qhi, Qlo, Khi, Klo, Vt,
                                                        Opart, mpart, lpart, chunk);
    combine<<<(N_SEQ * 16 + 255) / 256, 256, 0, stream>>>(Opart, mpart, lpart, out, nsplit);
}

// Round 8
// 188.390 us; speedup vs baseline: 1.2131x; 1.0365x over previous
//
#include <hip/hip_runtime.h>
#include <hip/hip_fp16.h>

#define N_SEQ 8192
#define E_DIM 768
#define D_OUT 64
#define PADK 68                       // 64 + 4 pad -> 136B rows: 2-way (free) bank aliasing
#define SCALE_LOG2 0.18033688011112042f   // 1/(8*ln2): fold softmax scale + log2e into Q

typedef __attribute__((ext_vector_type(8)))  short s16x8;
typedef __attribute__((ext_vector_type(4)))  float f32x4;
typedef __attribute__((ext_vector_type(16))) float f32x16;

static __device__ __forceinline__ unsigned short f2bf(float f) {
    union { float f; unsigned int u; } v; v.f = f;
    unsigned int r = v.u + 0x7FFFu + ((v.u >> 16) & 1u);   // RNE
    return (unsigned short)(r >> 16);
}
static __device__ __forceinline__ float bf2f(unsigned short h) {
    union { float f; unsigned int u; } v; v.u = ((unsigned int)h) << 16; return v.f;
}
// pack two f32 -> bf16x2 by truncation (bias cancels / compensated by lo term)
static __device__ __forceinline__ unsigned int packbf(float a, float b) {
    union { float f; unsigned int u; } x, y; x.f = a; y.f = b;
    return (y.u & 0xFFFF0000u) | (x.u >> 16);
}
static __device__ __forceinline__ s16x8 gfrag(const unsigned short* p) {
    union { uint4 u; s16x8 s; } r; r.u = *(const uint4*)p; return r.s;
}
static __device__ __forceinline__ s16x8 ldsfrag(const unsigned short* p) {
    union { uint2 u[2]; s16x8 s; } r;
    r.u[0] = *(const uint2*)(p);
    r.u[1] = *(const uint2*)(p + 4);
    return r.s;
}
static __device__ __forceinline__ void st32(unsigned short* d, uint4 a, uint4 b) {
    uint2* p = (uint2*)d;
    p[0] = make_uint2(a.x, a.y); p[1] = make_uint2(a.z, a.w);
    p[2] = make_uint2(b.x, b.y); p[3] = make_uint2(b.z, b.w);
}

// ---------------- Kernel 1: W -> Wt (transposed, bf16 hi/lo) -----------------
__global__ __launch_bounds__(256) void prep_w(const float* __restrict__ WQ,
                                              const float* __restrict__ WK,
                                              const float* __restrict__ WV,
                                              unsigned short* __restrict__ Wthi,
                                              unsigned short* __restrict__ Wtlo) {
    int idx = blockIdx.x * 256 + threadIdx.x;          // 192*768 exact
    int n = idx / E_DIM;
    int k = idx - n * E_DIM;
    float v;
    if (n < 64)       v = WQ[k * 64 + n];
    else if (n < 128) v = WK[k * 64 + (n - 64)];
    else              v = WV[k * 64 + (n - 128)];
    unsigned short hb = f2bf(v);
    Wthi[idx] = hb;
    Wtlo[idx] = f2bf(v - bf2f(hb));
}

// ---------------- Kernel 2: QKV projection (fp32 X, in-register split) -------
// Block = one 16-row m-tile; wave wv = 16-col block c=wv of D. The 4 waves
// share the same X rows (L1 hits). X hi/lo split in-register: hi = trunc,
// lo = RNE(v - hi) -> hi+lo accurate to 2^-17, ~32 VALU/step.
__global__ __launch_bounds__(256, 2) void proj_qkv(const float* __restrict__ X,
                                                   const unsigned short* __restrict__ Wthi,
                                                   const unsigned short* __restrict__ Wtlo,
                                                   unsigned short* __restrict__ Qhi,
                                                   unsigned short* __restrict__ Qlo,
                                                   unsigned short* __restrict__ Khi,
                                                   unsigned short* __restrict__ Klo,
                                                   unsigned short* __restrict__ Vt) {
    int tid  = threadIdx.x;
    int wv   = tid >> 6;
    int lane = tid & 63;
    int mt   = blockIdx.x;                   // 0..511
    int c    = wv;                           // 16-col block within D=64
    int m0 = mt * 16, n0 = c * 16;
    int lr = lane & 15, lk = lane >> 4;      // row-in-tile, k-quad

    f32x4 aQ, aK, aV;
    #pragma unroll
    for (int i = 0; i < 4; ++i) { aQ[i] = 0.f; aK[i] = 0.f; aV[i] = 0.f; }

    const float* xb = X + (size_t)(m0 + lr) * E_DIM + lk * 8;
    const unsigned short* wqh = Wthi + (size_t)(n0 + lr) * E_DIM + lk * 8;
    const unsigned short* wql = Wtlo + (size_t)(n0 + lr) * E_DIM + lk * 8;
    const unsigned short* wkh = Wthi + (size_t)(64 + n0 + lr) * E_DIM + lk * 8;
    const unsigned short* wkl = Wtlo + (size_t)(64 + n0 + lr) * E_DIM + lk * 8;
    const unsigned short* wvh = Wthi + (size_t)(128 + n0 + lr) * E_DIM + lk * 8;

    #pragma unroll 2
    for (int ks = 0; ks < E_DIM / 32; ++ks) {
        int kb = ks * 32;
        union { float4 f[2]; float s[8]; unsigned int u[8]; } xv;
        xv.f[0] = *(const float4*)(xb + kb);
        xv.f[1] = *(const float4*)(xb + kb + 4);
        // split: hi = trunc(v); lo = trunc(v - hi)  (compensated)
        union { unsigned int u[4]; s16x8 s; } ah, al;
        #pragma unroll
        for (int j = 0; j < 4; ++j) {
            union { unsigned int u; float f; } h0, h1;
            h0.u = xv.u[2 * j]     & 0xFFFF0000u;
            h1.u = xv.u[2 * j + 1] & 0xFFFF0000u;
            ah.u[j] = (xv.u[2 * j] >> 16) | (xv.u[2 * j + 1] & 0xFFFF0000u);
            al.u[j] = packbf(xv.s[2 * j] - h0.f, xv.s[2 * j + 1] - h1.f);
        }
        s16x8 bqh = gfrag(wqh + kb);
        s16x8 bql = gfrag(wql + kb);
        s16x8 bkh = gfrag(wkh + kb);
        s16x8 bkl = gfrag(wkl + kb);
        s16x8 bvh = gfrag(wvh + kb);
        aQ = __builtin_amdgcn_mfma_f32_16x16x32_bf16(ah.s, bqh, aQ, 0, 0, 0);
        aK = __builtin_amdgcn_mfma_f32_16x16x32_bf16(ah.s, bkh, aK, 0, 0, 0);
        aV = __builtin_amdgcn_mfma_f32_16x16x32_bf16(ah.s, bvh, aV, 0, 0, 0);
        aQ = __builtin_amdgcn_mfma_f32_16x16x32_bf16(ah.s, bql, aQ, 0, 0, 0);
        aK = __builtin_amdgcn_mfma_f32_16x16x32_bf16(ah.s, bkl, aK, 0, 0, 0);
        aQ = __builtin_amdgcn_mfma_f32_16x16x32_bf16(al.s, bqh, aQ, 0, 0, 0);
        aK = __builtin_amdgcn_mfma_f32_16x16x32_bf16(al.s, bkh, aK, 0, 0, 0);
    }

    // C/D layout (16x16): col = lane&15, row = (lane>>4)*4 + r  [m89/m91]
    #pragma unroll
    for (int r = 0; r < 4; ++r) {
        int grow = m0 + lk * 4 + r, gcol = n0 + lr;
        float q = aQ[r] * SCALE_LOG2;
        unsigned short hb = f2bf(q);
        Qhi[(size_t)grow * 64 + gcol] = hb;
        Qlo[(size_t)grow * 64 + gcol] = f2bf(q - bf2f(hb));
        float v = aK[r];
        hb = f2bf(v);
        Khi[(size_t)grow * 64 + gcol] = hb;
        Klo[(size_t)grow * 64 + gcol] = f2bf(v - bf2f(hb));
    }
    ushort4 pk;                          // V: 4 consecutive rows -> one 8B store
    pk.x = f2bf(aV[0]); pk.y = f2bf(aV[1]);
    pk.z = f2bf(aV[2]); pk.w = f2bf(aV[3]);
    *(ushort4*)(Vt + (size_t)(n0 + lr) * N_SEQ + m0 + lk * 4) = pk;
}

// ---------------- Kernel 3: flash attention (S^T, LDS dbuf, 1 barrier/tile) --
// grid (nsplit, 64); block 256 = 4 waves, each wave owns 32 Q-rows.
// Epoch it: [barrier][store tile it+1 -> buf 1-cur (regs prefetched an epoch
// ago)][compute tile it from buf cur]. WAR/RAW on each buffer separated by
// exactly one barrier. Prefetch loads drain at the NEXT barrier (compiler's
// vmcnt(0)) -> a full compute phase of latency cover.
__global__ __launch_bounds__(256, 3) void attn(const unsigned short* __restrict__ Qhi,
                                               const unsigned short* __restrict__ Qlo,
                                               const unsigned short* __restrict__ Khi,
                                               const unsigned short* __restrict__ Klo,
                                               const unsigned short* __restrict__ Vt,
                                               unsigned short* __restrict__ Opart,
                                               float* __restrict__ mpart,
                                               float* __restrict__ lpart,
                                               int chunk) {
    __shared__ unsigned short sK[2][128 * PADK];   // per buf: rows 0-63 Khi, 64-127 Klo
    __shared__ unsigned short sV[2][64 * PADK];    // per buf: [d][key]

    int tid = threadIdx.x, wv = tid >> 6, lane = tid & 63;
    int lrow = lane & 31, lh = lane >> 5;
    int c = blockIdx.x, qb = blockIdx.y;
    int q0 = qb * 128 + wv * 32;

    // Q fragments (whole D=64) resident in registers
    s16x8 qh[4], ql[4];
    #pragma unroll
    for (int ks = 0; ks < 4; ++ks) {
        int kb = ks * 16 + lh * 8;
        qh[ks] = gfrag(Qhi + (size_t)(q0 + lrow) * 64 + kb);
        ql[ks] = gfrag(Qlo + (size_t)(q0 + lrow) * 64 + kb);
    }

    f32x16 O0, O1;
    #pragma unroll
    for (int i = 0; i < 16; ++i) { O0[i] = 0.f; O1[i] = 0.f; }
    float mrow = -1e30f, lrun = 0.f;

    int steps = chunk >> 6;
    int srow = tid >> 2, sseg = tid & 3;    // staging: 64 rows x 4 segs x 16 elems

    uint4 rA0, rA1, rB0, rB1, rC0, rC1;
    // prefetch tile 0, store into buf 0 (no barrier: no prior readers)
    {
        int j1 = c * chunk;
        const uint4* ps = (const uint4*)(Khi + ((size_t)(j1 + srow) * 64 + sseg * 16));
        rA0 = ps[0]; rA1 = ps[1];
        ps = (const uint4*)(Klo + ((size_t)(j1 + srow) * 64 + sseg * 16));
        rB0 = ps[0]; rB1 = ps[1];
        ps = (const uint4*)(Vt + ((size_t)srow * N_SEQ + j1 + sseg * 16));
        rC0 = ps[0]; rC1 = ps[1];
    }
    st32(sK[0] + srow * PADK + sseg * 16, rA0, rA1);
    st32(sK[0] + (64 + srow) * PADK + sseg * 16, rB0, rB1);
    st32(sV[0] + srow * PADK + sseg * 16, rC0, rC1);
    if (steps > 1) {                         // prefetch tile 1
        int j1 = c * chunk + 64;
        const uint4* ps = (const uint4*)(Khi + ((size_t)(j1 + srow) * 64 + sseg * 16));
        rA0 = ps[0]; rA1 = ps[1];
        ps = (const uint4*)(Klo + ((size_t)(j1 + srow) * 64 + sseg * 16));
        rB0 = ps[0]; rB1 = ps[1];
        ps = (const uint4*)(Vt + ((size_t)srow * N_SEQ + j1 + sseg * 16));
        rC0 = ps[0]; rC1 = ps[1];
    }

    for (int it = 0; it < steps; ++it) {
        int cur = it & 1;
        __syncthreads();                     // the ONE barrier per epoch
        if (it + 1 < steps) {                // store tile it+1 into the other buf
            st32(sK[1 - cur] + srow * PADK + sseg * 16, rA0, rA1);
            st32(sK[1 - cur] + (64 + srow) * PADK + sseg * 16, rB0, rB1);
            st32(sV[1 - cur] + srow * PADK + sseg * 16, rC0, rC1);
            if (it + 2 < steps) {            // prefetch tile it+2
                int j1 = c * chunk + (it + 2) * 64;
                const uint4* ps = (const uint4*)(Khi + ((size_t)(j1 + srow) * 64 + sseg * 16));
                rA0 = ps[0]; rA1 = ps[1];
                ps = (const uint4*)(Klo + ((size_t)(j1 + srow) * 64 + sseg * 16));
                rB0 = ps[0]; rB1 = ps[1];
                ps = (const uint4*)(Vt + ((size_t)srow * N_SEQ + j1 + sseg * 16));
                rC0 = ps[0]; rC1 = ps[1];
            }
        }
        const unsigned short* sk = sK[cur];
        const unsigned short* sv = sV[cur];

        // S^T = K @ Q^T  (3-term split-bf16): s0 keys 0-31, s1 keys 32-63
        f32x16 s0, s1;
        #pragma unroll
        for (int i = 0; i < 16; ++i) { s0[i] = 0.f; s1[i] = 0.f; }
        #pragma unroll
        for (int ks = 0; ks < 4; ++ks) {
            int kb = ks * 16 + lh * 8;
            s16x8 b0h = ldsfrag(sk + (size_t)lrow * PADK + kb);
            s16x8 b0l = ldsfrag(sk + (size_t)(64 + lrow) * PADK + kb);
            s0 = __builtin_amdgcn_mfma_f32_32x32x16_bf16(b0h, qh[ks], s0, 0, 0, 0);
            s0 = __builtin_amdgcn_mfma_f32_32x32x16_bf16(b0l, qh[ks], s0, 0, 0, 0);
            s0 = __builtin_amdgcn_mfma_f32_32x32x16_bf16(b0h, ql[ks], s0, 0, 0, 0);
            s16x8 b1h = ldsfrag(sk + (size_t)(32 + lrow) * PADK + kb);
            s16x8 b1l = ldsfrag(sk + (size_t)(96 + lrow) * PADK + kb);
            s1 = __builtin_amdgcn_mfma_f32_32x32x16_bf16(b1h, qh[ks], s1, 0, 0, 0);
            s1 = __builtin_amdgcn_mfma_f32_32x32x16_bf16(b1l, qh[ks], s1, 0, 0, 0);
            s1 = __builtin_amdgcn_mfma_f32_32x32x16_bf16(b1h, ql[ks], s1, 0, 0, 0);
        }

        // in-lane row max (this lane's query = lrow; other 32 keys in lane^32)
        float rm = fmaxf(s0[0], s1[0]);
        #pragma unroll
        for (int i = 1; i < 16; ++i) rm = fmaxf(rm, fmaxf(s0[i], s1[i]));
        rm = fmaxf(rm, __shfl_xor(rm, 32, 64));
        float mn  = fmaxf(mrow, rm);
        float alf = exp2f(mrow - mn);
        mrow = mn;

        // p = exp2(s - m) in place; partial row-sum
        float psum = 0.f;
        #pragma unroll
        for (int i = 0; i < 16; ++i) { s0[i] = exp2f(s0[i] - mn); psum += s0[i]; }
        #pragma unroll
        for (int i = 0; i < 16; ++i) { s1[i] = exp2f(s1[i] - mn); psum += s1[i]; }
        lrun = lrun * alf + psum;

        // pack P to bf16 pairs; lane^32 swap builds A-frags (query=m)
        unsigned int I[16], J[16];
        #pragma unroll
        for (int q4 = 0; q4 < 4; ++q4) {
            I[2 * q4]         = packbf(s0[4 * q4],     s0[4 * q4 + 1]);
            I[2 * q4 + 1]     = packbf(s0[4 * q4 + 2], s0[4 * q4 + 3]);
            I[8 + 2 * q4]     = packbf(s1[4 * q4],     s1[4 * q4 + 1]);
            I[8 + 2 * q4 + 1] = packbf(s1[4 * q4 + 2], s1[4 * q4 + 3]);
        }
        #pragma unroll
        for (int i = 0; i < 16; ++i) J[i] = (unsigned int)__shfl_xor((int)I[i], 32, 64);
        s16x8 a[4];
        #pragma unroll
        for (int ks = 0; ks < 4; ++ks) {
            int b = (ks >> 1) * 8 + (ks & 1) * 4;
            union { unsigned int u[4]; s16x8 s; } fa;
            fa.u[0] = lh ? J[b + 2] : I[b];
            fa.u[1] = lh ? J[b + 3] : I[b + 1];
            fa.u[2] = lh ? I[b + 2] : J[b];
            fa.u[3] = lh ? I[b + 3] : J[b + 1];
            a[ks] = fa.s;
        }

        // rescale O only when some query's max moved (skip when alf==1)
        if (__any(alf != 1.0f)) {
            #pragma unroll
            for (int r = 0; r < 16; ++r) {
                int qr = (r & 3) + 8 * (r >> 2) + 4 * lh;
                float af = __shfl(alf, qr, 64);
                O0[r] *= af; O1[r] *= af;
            }
        }

        // O += P @ V
        #pragma unroll
        for (int ks = 0; ks < 4; ++ks) {
            int kb = ks * 16 + lh * 8;
            s16x8 b0 = ldsfrag(sv + (size_t)lrow * PADK + kb);
            s16x8 b1 = ldsfrag(sv + (size_t)(32 + lrow) * PADK + kb);
            O0 = __builtin_amdgcn_mfma_f32_32x32x16_bf16(a[ks], b0, O0, 0, 0, 0);
            O1 = __builtin_amdgcn_mfma_f32_32x32x16_bf16(a[ks], b1, O1, 0, 0, 0);
        }
    }

    // store partials (O as bf16: halves split-K traffic)
    #pragma unroll
    for (int r = 0; r < 16; ++r) {
        int row = (r & 3) + 8 * (r >> 2) + 4 * lh;
        int grow = q0 + row;
        size_t ob = ((size_t)c * N_SEQ + grow) * 64;
        Opart[ob + lrow]      = f2bf(O0[r]);
        Opart[ob + 32 + lrow] = f2bf(O1[r]);
    }
    float lfull = lrun + __shfl_xor(lrun, 32, 64);
    if (lane < 32) {
        int grow = q0 + lrow;
        mpart[c * N_SEQ + grow] = mrow;
        lpart[c * N_SEQ + grow] = lfull;
    }
}

// ---------------- Kernel 4: combine split-K partials (bf16 partials) ---------
__global__ __launch_bounds__(256) void combine(const unsigned short* __restrict__ Opart,
                                               const float* __restrict__ mpart,
                                               const float* __restrict__ lpart,
                                               float* __restrict__ out,
                                               int nsplit) {
    int idx = blockIdx.x * 256 + threadIdx.x;    // N_SEQ*16
    int row = idx >> 4, d4 = idx & 15;
    float M = -1e30f;
    #pragma unroll 4
    for (int c = 0; c < nsplit; ++c) M = fmaxf(M, mpart[c * N_SEQ + row]);
    float4 num = make_float4(0.f, 0.f, 0.f, 0.f);
    float den = 0.f;
    #pragma unroll 4
    for (int c = 0; c < nsplit; ++c) {
        float w = exp2f(mpart[c * N_SEQ + row] - M);
        den += w * lpart[c * N_SEQ + row];
        ushort4 o = *(const ushort4*)(Opart + ((size_t)c * N_SEQ + row) * 64 + d4 * 4);
        num.x += w * bf2f(o.x); num.y += w * bf2f(o.y);
        num.z += w * bf2f(o.z); num.w += w * bf2f(o.w);
    }
    float inv = 1.0f / den;
    num.x *= inv; num.y *= inv; num.z *= inv; num.w *= inv;
    ((float4*)out)[idx] = num;
}

extern "C" void kernel_launch(void* const* d_in, const int* in_sizes, int n_in,
                              void* d_out, int out_size, void* d_ws, size_t ws_size,
                              hipStream_t stream) {
    const float* X  = (const float*)d_in[0];
    const float* WQ = (const float*)d_in[1];
    const float* WK = (const float*)d_in[2];
    const float* WV = (const float*)d_in[3];
    float* out = (float*)d_out;

    // workspace carve
    const size_t szQK = (size_t)N_SEQ * 64 * 2;      // 1 MB each (bf16)
    const size_t szW  = (size_t)192 * E_DIM * 2;     // 288 KB each
    char* p = (char*)d_ws;
    unsigned short* Qhi = (unsigned short*)p; p += szQK;
    unsigned short* Qlo = (unsigned short*)p; p += szQK;
    unsigned short* Khi = (unsigned short*)p; p += szQK;
    unsigned short* Klo = (unsigned short*)p; p += szQK;
    unsigned short* Vt  = (unsigned short*)p; p += szQK;
    unsigned short* Wthi = (unsigned short*)p; p += szW;
    unsigned short* Wtlo = (unsigned short*)p; p += szW;
    size_t base = (size_t)(p - (char*)d_ws);
    size_t per  = (size_t)N_SEQ * 64 * 2 + 2 * (size_t)N_SEQ * 4;  // bf16 Opart + m + l
    int nsplit = 16;
    while (nsplit > 1 && base + (size_t)nsplit * per > ws_size) nsplit >>= 1;
    float* mpart = (float*)p; p += (size_t)nsplit * N_SEQ * 4;
    float* lpart = (float*)p; p += (size_t)nsplit * N_SEQ * 4;
    unsigned short* Opart = (unsigned short*)p;

    int chunk = N_SEQ / nsplit;

    prep_w<<<(192 * E_DIM) / 256, 256, 0, stream>>>(WQ, WK, WV, Wthi, Wtlo);
    proj_qkv<<<512, 256, 0, stream>>>(X, Wthi, Wtlo, Qhi, Qlo, Khi, Klo, Vt);
    attn<<<dim3(nsplit, N_SEQ / 128), 256, 0, stream>>>(Qhi, Qlo, Khi, Klo, Vt,
                                                        Opart, mpart, lpart, chunk);
    combine<<<(N_SEQ * 16 + 255) / 256, 256, 0, stream>>>(Opart, mpart, lpart, out, nsplit);
}

// Round 9
// 179.703 us; speedup vs baseline: 1.2717x; 1.0483x over previous
//
#include <hip/hip_runtime.h>
#include <hip/hip_fp16.h>

#define N_SEQ 8192
#define E_DIM 768
#define D_OUT 64
#define SCALE_LOG2 0.18033688011112042f   // 1/(8*ln2): fold softmax scale + log2e into Q

typedef __attribute__((ext_vector_type(8)))  short s16x8;
typedef __attribute__((ext_vector_type(4)))  float f32x4;
typedef __attribute__((ext_vector_type(16))) float f32x16;

static __device__ __forceinline__ unsigned short f2bf(float f) {
    union { float f; unsigned int u; } v; v.f = f;
    unsigned int r = v.u + 0x7FFFu + ((v.u >> 16) & 1u);   // RNE
    return (unsigned short)(r >> 16);
}
static __device__ __forceinline__ float bf2f(unsigned short h) {
    union { float f; unsigned int u; } v; v.u = ((unsigned int)h) << 16; return v.f;
}
// pack two f32 -> bf16x2 by truncation (bias cancels / compensated by lo term)
static __device__ __forceinline__ unsigned int packbf(float a, float b) {
    union { float f; unsigned int u; } x, y; x.f = a; y.f = b;
    return (y.u & 0xFFFF0000u) | (x.u >> 16);
}
static __device__ __forceinline__ s16x8 gfrag(const unsigned short* p) {
    union { uint4 u; s16x8 s; } r; r.u = *(const uint4*)p; return r.s;
}

// ---------------- Kernel 1: W -> Wt (transposed, bf16 hi/lo) -----------------
__global__ __launch_bounds__(256) void prep_w(const float* __restrict__ WQ,
                                              const float* __restrict__ WK,
                                              const float* __restrict__ WV,
                                              unsigned short* __restrict__ Wthi,
                                              unsigned short* __restrict__ Wtlo) {
    int idx = blockIdx.x * 256 + threadIdx.x;          // 192*768 exact
    int n = idx / E_DIM;
    int k = idx - n * E_DIM;
    float v;
    if (n < 64)       v = WQ[k * 64 + n];
    else if (n < 128) v = WK[k * 64 + (n - 64)];
    else              v = WV[k * 64 + (n - 128)];
    unsigned short hb = f2bf(v);
    Wthi[idx] = hb;
    Wtlo[idx] = f2bf(v - bf2f(hb));
}

// ---------------- Kernel 2: QKV projection -> fragment-native K/V ------------
// Block = one 16-row m-tile; wave wv = 16-col block of D. Q stored row-major
// hi/lo; K stored as KA: per 64-key tile J, per (hl, half, ks), 64 lanes x
// 8 bf16 in MFMA A-frag order (key = half*32 + (lane&31), d = ks*16 +
// (lane>>5)*8 + j). V stored as VB: B-frag order (d = half*32 + (lane&31),
// key = ks*16 + (lane>>5)*8 + j). Attn then loads every fragment as ONE
// coalesced global_load_dwordx4 (lane*16B contiguous).
__global__ __launch_bounds__(256, 2) void proj_qkv(const float* __restrict__ X,
                                                   const unsigned short* __restrict__ Wthi,
                                                   const unsigned short* __restrict__ Wtlo,
                                                   unsigned short* __restrict__ Qhi,
                                                   unsigned short* __restrict__ Qlo,
                                                   unsigned short* __restrict__ KA,
                                                   unsigned short* __restrict__ VB) {
    int tid  = threadIdx.x;
    int wv   = tid >> 6;
    int lane = tid & 63;
    int mt   = blockIdx.x;                   // 0..511
    int m0 = mt * 16, n0 = wv * 16;
    int lr = lane & 15, lk = lane >> 4;      // row-in-tile, k-quad

    f32x4 aQ, aK, aV;
    #pragma unroll
    for (int i = 0; i < 4; ++i) { aQ[i] = 0.f; aK[i] = 0.f; aV[i] = 0.f; }

    const float* xb = X + (size_t)(m0 + lr) * E_DIM + lk * 8;
    const unsigned short* wqh = Wthi + (size_t)(n0 + lr) * E_DIM + lk * 8;
    const unsigned short* wql = Wtlo + (size_t)(n0 + lr) * E_DIM + lk * 8;
    const unsigned short* wkh = Wthi + (size_t)(64 + n0 + lr) * E_DIM + lk * 8;
    const unsigned short* wkl = Wtlo + (size_t)(64 + n0 + lr) * E_DIM + lk * 8;
    const unsigned short* wvh = Wthi + (size_t)(128 + n0 + lr) * E_DIM + lk * 8;

    #pragma unroll 2
    for (int ks = 0; ks < E_DIM / 32; ++ks) {
        int kb = ks * 32;
        union { float4 f[2]; float s[8]; unsigned int u[8]; } xv;
        xv.f[0] = *(const float4*)(xb + kb);
        xv.f[1] = *(const float4*)(xb + kb + 4);
        union { unsigned int u[4]; s16x8 s; } ah, al;
        #pragma unroll
        for (int j = 0; j < 4; ++j) {
            union { unsigned int u; float f; } h0, h1;
            h0.u = xv.u[2 * j]     & 0xFFFF0000u;
            h1.u = xv.u[2 * j + 1] & 0xFFFF0000u;
            ah.u[j] = (xv.u[2 * j] >> 16) | (xv.u[2 * j + 1] & 0xFFFF0000u);
            al.u[j] = packbf(xv.s[2 * j] - h0.f, xv.s[2 * j + 1] - h1.f);
        }
        s16x8 bqh = gfrag(wqh + kb);
        s16x8 bql = gfrag(wql + kb);
        s16x8 bkh = gfrag(wkh + kb);
        s16x8 bkl = gfrag(wkl + kb);
        s16x8 bvh = gfrag(wvh + kb);
        aQ = __builtin_amdgcn_mfma_f32_16x16x32_bf16(ah.s, bqh, aQ, 0, 0, 0);
        aK = __builtin_amdgcn_mfma_f32_16x16x32_bf16(ah.s, bkh, aK, 0, 0, 0);
        aV = __builtin_amdgcn_mfma_f32_16x16x32_bf16(ah.s, bvh, aV, 0, 0, 0);
        aQ = __builtin_amdgcn_mfma_f32_16x16x32_bf16(ah.s, bql, aQ, 0, 0, 0);
        aK = __builtin_amdgcn_mfma_f32_16x16x32_bf16(ah.s, bkl, aK, 0, 0, 0);
        aQ = __builtin_amdgcn_mfma_f32_16x16x32_bf16(al.s, bqh, aQ, 0, 0, 0);
        aK = __builtin_amdgcn_mfma_f32_16x16x32_bf16(al.s, bkh, aK, 0, 0, 0);
    }

    // C/D layout (16x16): col = lane&15, row = (lane>>4)*4 + r  [m89/m91]
    // ---- Q: row-major hi/lo
    #pragma unroll
    for (int r = 0; r < 4; ++r) {
        int grow = m0 + lk * 4 + r, gcol = n0 + lr;
        float q = aQ[r] * SCALE_LOG2;
        unsigned short hb = f2bf(q);
        Qhi[(size_t)grow * 64 + gcol] = hb;
        Qlo[(size_t)grow * 64 + gcol] = f2bf(q - bf2f(hb));
    }
    // ---- K: frag-native scatter (hl=0 at o, hl=1 at o+4096)
    {
        int ks_ = n0 >> 4;                 // d-segment
        int lh  = lr >> 3;
        int j   = lr & 7;
        #pragma unroll
        for (int r = 0; r < 4; ++r) {
            int grow = m0 + lk * 4 + r;
            int J    = grow >> 6;
            int half = (grow >> 5) & 1;
            int mloc = grow & 31;
            size_t o = ((((size_t)J * 4) + half) * 4 + ks_) * 512
                     + (size_t)(mloc + 32 * lh) * 8 + j;
            float v = aK[r];
            unsigned short hb = f2bf(v);
            KA[o]        = hb;                       // hi
            KA[o + 4096] = f2bf(v - bf2f(hb));       // lo (hl stride = 2*4*512)
        }
    }
    // ---- V: frag-native, 4 consecutive j -> one 8B store
    {
        int J      = mt >> 2;
        int half_v = n0 >> 5;
        int ks_v   = mt & 3;
        int lane_v = (n0 & 16) + lr + 32 * (lk >> 1);
        int jbase  = (lk & 1) * 4;
        ushort4 pk;
        pk.x = f2bf(aV[0]); pk.y = f2bf(aV[1]);
        pk.z = f2bf(aV[2]); pk.w = f2bf(aV[3]);
        *(ushort4*)(VB + (((size_t)J * 2 + half_v) * 4 + ks_v) * 512
                       + (size_t)lane_v * 8 + jbase) = pk;
    }
}

// ---------------- Kernel 3: flash attention — no LDS, no barriers ------------
// grid (nsplit, 64); block 256 = 4 waves, each wave owns 32 Q-rows and
// free-runs over its tile range. Every K/V fragment is one coalesced
// global_load_dwordx4 from the frag-native arrays (L2-resident, 3 MB).
// Waves overlap loads/MFMA/VALU individually via vmcnt(N) — no convoy.
__global__ __launch_bounds__(256, 3) void attn(const unsigned short* __restrict__ Qhi,
                                               const unsigned short* __restrict__ Qlo,
                                               const unsigned short* __restrict__ KA,
                                               const unsigned short* __restrict__ VB,
                                               unsigned short* __restrict__ Opart,
                                               float* __restrict__ mpart,
                                               float* __restrict__ lpart,
                                               int nsplit) {
    int tid = threadIdx.x, wv = tid >> 6, lane = tid & 63;
    int lrow = lane & 31, lh = lane >> 5;
    int c = blockIdx.x, qb = blockIdx.y;
    int q0 = qb * 128 + wv * 32;

    // tile range for this chunk (128 tiles of 64 keys over nsplit chunks)
    int base = 128 / nsplit, rem = 128 - base * nsplit;
    int t0 = c * base + (c < rem ? c : rem);
    int t1 = t0 + base + (c < rem ? 1 : 0);

    // Q fragments (whole D=64) resident in registers
    s16x8 qh[4], ql[4];
    #pragma unroll
    for (int ks = 0; ks < 4; ++ks) {
        int kb = ks * 16 + lh * 8;
        qh[ks] = gfrag(Qhi + (size_t)(q0 + lrow) * 64 + kb);
        ql[ks] = gfrag(Qlo + (size_t)(q0 + lrow) * 64 + kb);
    }

    f32x16 O0, O1;
    #pragma unroll
    for (int i = 0; i < 16; ++i) { O0[i] = 0.f; O1[i] = 0.f; }
    float mrow = -1e30f, lrun = 0.f;

    for (int J = t0; J < t1; ++J) {
        const unsigned short* ka = KA + (size_t)J * 8192 + (size_t)lane * 8;
        const unsigned short* vb = VB + (size_t)J * 4096 + (size_t)lane * 8;

        // S^T = K @ Q^T (3-term split-bf16); frag loads are 1KB coalesced
        f32x16 s0, s1;
        #pragma unroll
        for (int i = 0; i < 16; ++i) { s0[i] = 0.f; s1[i] = 0.f; }
        #pragma unroll
        for (int ks = 0; ks < 4; ++ks) {
            // layout: (((J*2+hl)*2+half)*4+ks)*512 ; hl stride 4096, half 2048
            s16x8 a0h = gfrag(ka + ks * 512);
            s16x8 a0l = gfrag(ka + 4096 + ks * 512);
            s16x8 a1h = gfrag(ka + 2048 + ks * 512);
            s16x8 a1l = gfrag(ka + 4096 + 2048 + ks * 512);
            s0 = __builtin_amdgcn_mfma_f32_32x32x16_bf16(a0h, qh[ks], s0, 0, 0, 0);
            s0 = __builtin_amdgcn_mfma_f32_32x32x16_bf16(a0l, qh[ks], s0, 0, 0, 0);
            s0 = __builtin_amdgcn_mfma_f32_32x32x16_bf16(a0h, ql[ks], s0, 0, 0, 0);
            s1 = __builtin_amdgcn_mfma_f32_32x32x16_bf16(a1h, qh[ks], s1, 0, 0, 0);
            s1 = __builtin_amdgcn_mfma_f32_32x32x16_bf16(a1l, qh[ks], s1, 0, 0, 0);
            s1 = __builtin_amdgcn_mfma_f32_32x32x16_bf16(a1h, ql[ks], s1, 0, 0, 0);
        }

        // issue V-frag loads now; softmax below covers their latency
        s16x8 vf[8];
        #pragma unroll
        for (int ks = 0; ks < 4; ++ks) {
            vf[ks]     = gfrag(vb + ks * 512);          // half=0 (d 0-31)
            vf[4 + ks] = gfrag(vb + 2048 + ks * 512);   // half=1 (d 32-63)
        }

        // in-lane row max (this lane's query = lrow; other 32 keys in lane^32)
        float rm = fmaxf(s0[0], s1[0]);
        #pragma unroll
        for (int i = 1; i < 16; ++i) rm = fmaxf(rm, fmaxf(s0[i], s1[i]));
        rm = fmaxf(rm, __shfl_xor(rm, 32, 64));
        float mn  = fmaxf(mrow, rm);
        float alf = exp2f(mrow - mn);
        mrow = mn;

        // p = exp2(s - m) in place; partial row-sum
        float psum = 0.f;
        #pragma unroll
        for (int i = 0; i < 16; ++i) { s0[i] = exp2f(s0[i] - mn); psum += s0[i]; }
        #pragma unroll
        for (int i = 0; i < 16; ++i) { s1[i] = exp2f(s1[i] - mn); psum += s1[i]; }
        lrun = lrun * alf + psum;

        // pack P to bf16 pairs; lane^32 swap builds A-frags (query=m)
        unsigned int I[16], Jx[16];
        #pragma unroll
        for (int q4 = 0; q4 < 4; ++q4) {
            I[2 * q4]         = packbf(s0[4 * q4],     s0[4 * q4 + 1]);
            I[2 * q4 + 1]     = packbf(s0[4 * q4 + 2], s0[4 * q4 + 3]);
            I[8 + 2 * q4]     = packbf(s1[4 * q4],     s1[4 * q4 + 1]);
            I[8 + 2 * q4 + 1] = packbf(s1[4 * q4 + 2], s1[4 * q4 + 3]);
        }
        #pragma unroll
        for (int i = 0; i < 16; ++i) Jx[i] = (unsigned int)__shfl_xor((int)I[i], 32, 64);
        s16x8 a[4];
        #pragma unroll
        for (int ks = 0; ks < 4; ++ks) {
            int b = (ks >> 1) * 8 + (ks & 1) * 4;
            union { unsigned int u[4]; s16x8 s; } fa;
            fa.u[0] = lh ? Jx[b + 2] : I[b];
            fa.u[1] = lh ? Jx[b + 3] : I[b + 1];
            fa.u[2] = lh ? I[b + 2] : Jx[b];
            fa.u[3] = lh ? I[b + 3] : Jx[b + 1];
            a[ks] = fa.s;
        }

        // rescale O only when some query's max moved (skip when alf==1)
        if (__any(alf != 1.0f)) {
            #pragma unroll
            for (int r = 0; r < 16; ++r) {
                int qr = (r & 3) + 8 * (r >> 2) + 4 * lh;
                float af = __shfl(alf, qr, 64);
                O0[r] *= af; O1[r] *= af;
            }
        }

        // O += P @ V
        #pragma unroll
        for (int ks = 0; ks < 4; ++ks) {
            O0 = __builtin_amdgcn_mfma_f32_32x32x16_bf16(a[ks], vf[ks],     O0, 0, 0, 0);
            O1 = __builtin_amdgcn_mfma_f32_32x32x16_bf16(a[ks], vf[4 + ks], O1, 0, 0, 0);
        }
    }

    // store partials (O as bf16: halves split-K traffic)
    #pragma unroll
    for (int r = 0; r < 16; ++r) {
        int row = (r & 3) + 8 * (r >> 2) + 4 * lh;
        int grow = q0 + row;
        size_t ob = ((size_t)c * N_SEQ + grow) * 64;
        Opart[ob + lrow]      = f2bf(O0[r]);
        Opart[ob + 32 + lrow] = f2bf(O1[r]);
    }
    float lfull = lrun + __shfl_xor(lrun, 32, 64);
    if (lane < 32) {
        int grow = q0 + lrow;
        mpart[c * N_SEQ + grow] = mrow;
        lpart[c * N_SEQ + grow] = lfull;
    }
}

// ---------------- Kernel 4: combine split-K partials (bf16 partials) ---------
__global__ __launch_bounds__(256) void combine(const unsigned short* __restrict__ Opart,
                                               const float* __restrict__ mpart,
                                               const float* __restrict__ lpart,
                                               float* __restrict__ out,
                                               int nsplit) {
    int idx = blockIdx.x * 256 + threadIdx.x;    // N_SEQ*16
    int row = idx >> 4, d4 = idx & 15;
    float M = -1e30f;
    #pragma unroll 4
    for (int c = 0; c < nsplit; ++c) M = fmaxf(M, mpart[c * N_SEQ + row]);
    float4 num = make_float4(0.f, 0.f, 0.f, 0.f);
    float den = 0.f;
    #pragma unroll 4
    for (int c = 0; c < nsplit; ++c) {
        float w = exp2f(mpart[c * N_SEQ + row] - M);
        den += w * lpart[c * N_SEQ + row];
        ushort4 o = *(const ushort4*)(Opart + ((size_t)c * N_SEQ + row) * 64 + d4 * 4);
        num.x += w * bf2f(o.x); num.y += w * bf2f(o.y);
        num.z += w * bf2f(o.z); num.w += w * bf2f(o.w);
    }
    float inv = 1.0f / den;
    num.x *= inv; num.y *= inv; num.z *= inv; num.w *= inv;
    ((float4*)out)[idx] = num;
}

extern "C" void kernel_launch(void* const* d_in, const int* in_sizes, int n_in,
                              void* d_out, int out_size, void* d_ws, size_t ws_size,
                              hipStream_t stream) {
    const float* X  = (const float*)d_in[0];
    const float* WQ = (const float*)d_in[1];
    const float* WK = (const float*)d_in[2];
    const float* WV = (const float*)d_in[3];
    float* out = (float*)d_out;

    // workspace carve
    const size_t szQ  = (size_t)N_SEQ * 64 * 2;          // 1 MB each (bf16)
    const size_t szKA = (size_t)128 * 8192 * 2;          // 2 MB frag-native K hi+lo
    const size_t szVB = (size_t)128 * 4096 * 2;          // 1 MB frag-native V
    const size_t szW  = (size_t)192 * E_DIM * 2;         // 288 KB each
    char* p = (char*)d_ws;
    unsigned short* Qhi = (unsigned short*)p; p += szQ;
    unsigned short* Qlo = (unsigned short*)p; p += szQ;
    unsigned short* KA  = (unsigned short*)p; p += szKA;
    unsigned short* VB  = (unsigned short*)p; p += szVB;
    unsigned short* Wthi = (unsigned short*)p; p += szW;
    unsigned short* Wtlo = (unsigned short*)p; p += szW;
    size_t basews = (size_t)(p - (char*)d_ws);
    size_t per  = (size_t)N_SEQ * 64 * 2 + 2 * (size_t)N_SEQ * 4;  // bf16 Opart + m + l
    int nsplit = 12;
    while (nsplit > 1 && basews + (size_t)nsplit * per > ws_size) nsplit >>= 1;
    float* mpart = (float*)p; p += (size_t)nsplit * N_SEQ * 4;
    float* lpart = (float*)p; p += (size_t)nsplit * N_SEQ * 4;
    unsigned short* Opart = (unsigned short*)p;

    prep_w<<<(192 * E_DIM) / 256, 256, 0, stream>>>(WQ, WK, WV, Wthi, Wtlo);
    proj_qkv<<<512, 256, 0, stream>>>(X, Wthi, Wtlo, Qhi, Qlo, KA, VB);
    attn<<<dim3(nsplit, N_SEQ / 128), 256, 0, stream>>>(Qhi, Qlo, KA, VB,
                                                        Opart, mpart, lpart, nsplit);
    combine<<<(N_SEQ * 16 + 255) / 256, 256, 0, stream>>>(Opart, mpart, lpart, out, nsplit);
}